// Round 16
// baseline (466.511 us; speedup 1.0000x reference)
//
#include <hip/hip_runtime.h>
#include <stdint.h>
#include <stddef.h>

typedef __attribute__((ext_vector_type(8))) short bf16x8;
typedef __attribute__((ext_vector_type(4))) float f32x4;
typedef __attribute__((ext_vector_type(4))) uint32_t u32x4;

#define DEVINL static __device__ __forceinline__

DEVINL float b2f(uint16_t u) {
  uint32_t x = ((uint32_t)u) << 16;
  float f;
  __builtin_memcpy(&f, &x, 4);
  return f;
}

DEVINL uint16_t f2b(float f) {
  uint32_t u;
  __builtin_memcpy(&u, &f, 4);
  return (uint16_t)((u + 0x7fffu + ((u >> 16) & 1u)) >> 16);
}

DEVINL void gload16(const void* gsrc, void* ldst) {
  __builtin_amdgcn_global_load_lds(
      (const __attribute__((address_space(1))) void*)gsrc,
      (__attribute__((address_space(3))) void*)ldst, 16, 0, 0);
}

// ---------------- runtime dtype/mask detection ----------------
__global__ void detect_kernel(const void* __restrict__ wq, const void* __restrict__ mask,
                              const void* __restrict__ bq, const void* __restrict__ bk,
                              const void* __restrict__ bv, const void* __restrict__ bo,
                              int* __restrict__ hdr, float* __restrict__ bias) {
  __shared__ int sflag, smask32, slen[8];
  const int tid = threadIdx.x;
  if (tid == 0) { sflag = 0; smask32 = 0; }
  if (tid < 8) slen[tid] = 0;
  __syncthreads();
  const uint16_t* w16 = (const uint16_t*)wq;
  int f = 0;
  for (int i = tid; i < 4096; i += 256) {
    uint16_t u = w16[i];
    uint32_t e = (u >> 7) & 0xFFu;
    if (fabsf(b2f(u)) > 0.25f || e == 0xFFu) f = 1;
  }
  if (f) atomicOr(&sflag, 1);
  const uint8_t* mb = (const uint8_t*)mask;
  int m32 = 0;
  for (int i = tid; i < 8191; i += 256) {
    if ((i & 1023) != 1023 && mb[i] != 0 && mb[i + 1] == 0) m32 = 1;
  }
  if (m32) atomicOr(&smask32, 1);
  __syncthreads();
  if (smask32) {
    const int* mi = (const int*)mask;
    for (int i = tid; i < 8192; i += 256) { if (mi[i] == 0) atomicAdd(&slen[i >> 10], 1); }
  } else {
    for (int i = tid; i < 8192; i += 256) { if (mb[i] == 0) atomicAdd(&slen[i >> 10], 1); }
  }
  __syncthreads();
  if (tid == 0) hdr[0] = sflag;
  if (tid < 8) hdr[1 + tid] = slen[tid];
  const void* bs[4] = {bq, bk, bv, bo};
  for (int j = 0; j < 4; ++j) {
    for (int i = tid; i < 1024; i += 256) {
      float v = sflag ? ((const float*)bs[j])[i] : b2f(((const uint16_t*)bs[j])[i]);
      bias[j * 1024 + i] = v;
    }
  }
}

// ---------------- fp32 -> bf16 conversion pass (or bf16 copy) ----------------
__global__ __launch_bounds__(256)
void convert_kernel(const void* __restrict__ s0, const void* __restrict__ s1,
                    const void* __restrict__ s2, const void* __restrict__ s3,
                    const void* __restrict__ s4, const void* __restrict__ s5,
                    uint16_t* __restrict__ d0, uint16_t* __restrict__ d1,
                    uint16_t* __restrict__ d2, const int* __restrict__ hdr, int doW) {
  const int isf = hdr[0];
  const size_t n01 = 1048576;
  const size_t nw = 131072;
  const size_t total = doW ? (2 * n01 + 4 * nw) : (2 * n01);
  size_t gid = (size_t)blockIdx.x * 256 + threadIdx.x;
  const size_t stride = (size_t)gridDim.x * 256;
  for (; gid < total; gid += stride) {
    const void* sp;
    uint16_t* dp;
    size_t off;
    if (gid < n01) { sp = s0; dp = d0; off = gid; }
    else if (gid < 2 * n01) { sp = s1; dp = d1; off = gid - n01; }
    else {
      const size_t w = (gid - 2 * n01) >> 17;
      off = (gid - 2 * n01) & (nw - 1);
      sp = (w == 0) ? s2 : (w == 1) ? s3 : (w == 2) ? s4 : s5;
      dp = d2 + w * 1048576;
    }
    if (isf) {
      const float* fp = (const float*)sp + off * 8;
      const f32x4 a = *(const f32x4*)fp;
      const f32x4 c = *(const f32x4*)(fp + 4);
      u32x4 r;
      r[0] = (uint32_t)f2b(a[0]) | ((uint32_t)f2b(a[1]) << 16);
      r[1] = (uint32_t)f2b(a[2]) | ((uint32_t)f2b(a[3]) << 16);
      r[2] = (uint32_t)f2b(c[0]) | ((uint32_t)f2b(c[1]) << 16);
      r[3] = (uint32_t)f2b(c[2]) | ((uint32_t)f2b(c[3]) << 16);
      *(u32x4*)(dp + off * 8) = r;
    } else {
      *(u32x4*)(dp + off * 8) = *(const u32x4*)((const uint16_t*)sp + off * 8);
    }
  }
}

// ---------------- GEMM core pieces ----------------
enum { MQ = 0, MK = 1, MV = 2, MO = 3 };

DEVINL u32x4 load8w(const void* __restrict__ src, bool f32, size_t eoff) {
  if (!f32) {
    return *(const u32x4*)((const uint16_t*)src + eoff);
  }
  const float* p = (const float*)src + eoff;
  const f32x4 a = *(const f32x4*)p;
  const f32x4 c = *(const f32x4*)(p + 4);
  u32x4 r;
  r[0] = (uint32_t)f2b(a[0]) | ((uint32_t)f2b(a[1]) << 16);
  r[1] = (uint32_t)f2b(a[2]) | ((uint32_t)f2b(a[3]) << 16);
  r[2] = (uint32_t)f2b(c[0]) | ((uint32_t)f2b(c[1]) << 16);
  r[3] = (uint32_t)f2b(c[2]) | ((uint32_t)f2b(c[3]) << 16);
  return r;
}

// ---------------- merged Q/K/V GEMM (double-buffered, issue-early pipeline) ----------------
__global__ __launch_bounds__(256)
void gemm_qkv(const uint16_t* __restrict__ dec_b, const uint16_t* __restrict__ src_b,
              const void* __restrict__ Wq, const void* __restrict__ Wk,
              const void* __restrict__ Wv, const float* __restrict__ bias,
              const int* __restrict__ hdr, uint16_t* __restrict__ Q,
              uint16_t* __restrict__ K, uint16_t* __restrict__ V, int wIsBf16) {
  __shared__ __align__(16) uint16_t lA[2][8192];
  __shared__ __align__(16) uint16_t lB[2][8192];
  const int tid = threadIdx.x, lane = tid & 63, wave = tid >> 6;
  const int bm = blockIdx.x;
  const int grp = blockIdx.y >> 3, bn = blockIdx.y & 7;
  const int isf = hdr[0];
  const bool wF32 = (wIsBf16 == 0) && (isf != 0);
  const uint16_t* Ab = (grp == 0) ? dec_b : src_b;
  const void* Wr = (grp == 0) ? Wq : (grp == 1) ? Wk : Wv;
  const float* bs = bias + grp * 1024;
  const float scale = (grp == 0) ? 0.125f : 1.f;
  const int wm = wave >> 1, wn = wave & 1;
  const int g = lane >> 4, cc = lane & 15;
  const int lr = lane >> 3, lc = lane & 7;
  const int scc = (lc ^ lr) * 8;

  auto stage = [&](int kt, int buf) {
#pragma unroll
    for (int q = 0; q < 4; ++q) {
      const int j = wave * 4 + q;
      gload16(Ab + (size_t)(bm * 128 + j * 8 + lr) * 1024 + kt * 64 + scc, &lA[buf][j * 512]);
    }
    if (!wF32) {
#pragma unroll
      for (int q = 0; q < 4; ++q) {
        const int j = wave * 4 + q;
        gload16((const uint16_t*)Wr + (size_t)(bn * 128 + j * 8 + lr) * 1024 + kt * 64 + scc, &lB[buf][j * 512]);
      }
    } else {
#pragma unroll
      for (int q = 0; q < 4; ++q) {
        const int j = wave * 4 + q;
        const u32x4 rv = load8w(Wr, true, (size_t)(bn * 128 + j * 8 + lr) * 1024 + kt * 64 + lc * 8);
        *(u32x4*)&lB[buf][j * 512 + lr * 64 + ((lc ^ lr) * 8)] = rv;
      }
    }
  };

  f32x4 acc[4][4];
#pragma unroll
  for (int i = 0; i < 4; ++i)
#pragma unroll
    for (int j = 0; j < 4; ++j) acc[i][j] = (f32x4){0.f, 0.f, 0.f, 0.f};

  stage(0, 0);
  for (int kt = 0; kt < 16; ++kt) {
    const int cur = kt & 1;
    asm volatile("s_waitcnt vmcnt(0) lgkmcnt(0)" ::: "memory");
    __builtin_amdgcn_sched_barrier(0);
    __builtin_amdgcn_s_barrier();
    if (kt + 1 < 16) stage(kt + 1, cur ^ 1);
#pragma unroll
    for (int kk = 0; kk < 2; ++kk) {
      bf16x8 af[4], bfr[4];
#pragma unroll
      for (int mi = 0; mi < 4; ++mi) {
        const int row = wm * 64 + mi * 16 + cc;
        af[mi] = *(const bf16x8*)&lA[cur][row * 64 + (((kk * 4 + g) ^ (cc & 7)) << 3)];
      }
#pragma unroll
      for (int ni = 0; ni < 4; ++ni) {
        const int row = wn * 64 + ni * 16 + cc;
        bfr[ni] = *(const bf16x8*)&lB[cur][row * 64 + (((kk * 4 + g) ^ (cc & 7)) << 3)];
      }
#pragma unroll
      for (int mi = 0; mi < 4; ++mi)
#pragma unroll
        for (int ni = 0; ni < 4; ++ni)
          acc[mi][ni] = __builtin_amdgcn_mfma_f32_16x16x32_bf16(af[mi], bfr[ni], acc[mi][ni], 0, 0, 0);
    }
  }
#pragma unroll
  for (int mi = 0; mi < 4; ++mi) {
#pragma unroll
    for (int ni = 0; ni < 4; ++ni) {
      const int col = bn * 128 + wn * 64 + ni * 16 + cc;
      const float bv = bs[col];
      const int r0 = bm * 128 + wm * 64 + mi * 16 + g * 4;
#pragma unroll
      for (int r = 0; r < 4; ++r) {
        const int row = r0 + r;
        const float v = (acc[mi][ni][r] + bv) * scale;
        if (grp == 0) {        // rows = (b,t); Q[b][h][t][d]
          const int b = row >> 10, t = row & 1023, h = col >> 6, d = col & 63;
          Q[(((size_t)(b * 16 + h) << 10) + t) * 64 + d] = f2b(v);
        } else if (grp == 1) { // rows = (s,b); K[b][h][s][d]
          const int s = row >> 3, b = row & 7, h = col >> 6, d = col & 63;
          K[(((size_t)(b * 16 + h) << 10) + s) * 64 + d] = f2b(v);
        } else {               // V^T[b][h][d][s]
          const int s = row >> 3, b = row & 7, h = col >> 6, d = col & 63;
          V[(((size_t)(b * 16 + h) << 6) + d) * 1024 + s] = f2b(v);
        }
      }
    }
  }
}

// ---------------- output GEMM (double-buffered, issue-early pipeline) ----------------
template <int MODE>
__global__ __launch_bounds__(256)
void gemm_bt(const uint16_t* __restrict__ Ab, const void* __restrict__ Wr,
             const float* __restrict__ bias, const int* __restrict__ hdr,
             void* __restrict__ outp, float scale, int wIsBf16) {
  __shared__ __align__(16) uint16_t lA[2][8192];
  __shared__ __align__(16) uint16_t lB[2][8192];
  const int tid = threadIdx.x, lane = tid & 63, wave = tid >> 6;
  const int bm = blockIdx.x, bn = blockIdx.y;
  const int isf = hdr[0];
  const bool wF32 = (wIsBf16 == 0) && (isf != 0);
  const int wm = wave >> 1, wn = wave & 1;
  const int g = lane >> 4, cc = lane & 15;
  const int lr = lane >> 3, lc = lane & 7;
  const int scc = (lc ^ lr) * 8;

  auto stage = [&](int kt, int buf) {
#pragma unroll
    for (int q = 0; q < 4; ++q) {
      const int j = wave * 4 + q;
      gload16(Ab + (size_t)(bm * 128 + j * 8 + lr) * 1024 + kt * 64 + scc, &lA[buf][j * 512]);
    }
    if (!wF32) {
#pragma unroll
      for (int q = 0; q < 4; ++q) {
        const int j = wave * 4 + q;
        gload16((const uint16_t*)Wr + (size_t)(bn * 128 + j * 8 + lr) * 1024 + kt * 64 + scc, &lB[buf][j * 512]);
      }
    } else {
#pragma unroll
      for (int q = 0; q < 4; ++q) {
        const int j = wave * 4 + q;
        const u32x4 rv = load8w(Wr, true, (size_t)(bn * 128 + j * 8 + lr) * 1024 + kt * 64 + lc * 8);
        *(u32x4*)&lB[buf][j * 512 + lr * 64 + ((lc ^ lr) * 8)] = rv;
      }
    }
  };

  f32x4 acc[4][4];
#pragma unroll
  for (int i = 0; i < 4; ++i)
#pragma unroll
    for (int j = 0; j < 4; ++j) acc[i][j] = (f32x4){0.f, 0.f, 0.f, 0.f};

  stage(0, 0);
  for (int kt = 0; kt < 16; ++kt) {
    const int cur = kt & 1;
    asm volatile("s_waitcnt vmcnt(0) lgkmcnt(0)" ::: "memory");
    __builtin_amdgcn_sched_barrier(0);
    __builtin_amdgcn_s_barrier();
    if (kt + 1 < 16) stage(kt + 1, cur ^ 1);
#pragma unroll
    for (int kk = 0; kk < 2; ++kk) {
      bf16x8 af[4], bfr[4];
#pragma unroll
      for (int mi = 0; mi < 4; ++mi) {
        const int row = wm * 64 + mi * 16 + cc;
        af[mi] = *(const bf16x8*)&lA[cur][row * 64 + (((kk * 4 + g) ^ (cc & 7)) << 3)];
      }
#pragma unroll
      for (int ni = 0; ni < 4; ++ni) {
        const int row = wn * 64 + ni * 16 + cc;
        bfr[ni] = *(const bf16x8*)&lB[cur][row * 64 + (((kk * 4 + g) ^ (cc & 7)) << 3)];
      }
#pragma unroll
      for (int mi = 0; mi < 4; ++mi)
#pragma unroll
        for (int ni = 0; ni < 4; ++ni)
          acc[mi][ni] = __builtin_amdgcn_mfma_f32_16x16x32_bf16(af[mi], bfr[ni], acc[mi][ni], 0, 0, 0);
    }
  }
#pragma unroll
  for (int mi = 0; mi < 4; ++mi) {
#pragma unroll
    for (int ni = 0; ni < 4; ++ni) {
      const int col = bn * 128 + wn * 64 + ni * 16 + cc;
      const float bv = bias[col];
      const int r0 = bm * 128 + wm * 64 + mi * 16 + g * 4;
#pragma unroll
      for (int r = 0; r < 4; ++r) {
        const int row = r0 + r;
        const float v = (acc[mi][ni][r] + bv) * scale;
        const size_t o = (size_t)row * 1024 + col;
        if (isf) ((float*)outp)[o] = v;
        else ((uint16_t*)outp)[o] = f2b(v);
      }
    }
  }
}

// ---------------- fused attention (v16: NO K/V staging, direct L2 frags, 1 bar/phase) ----------------
// block = (b, t-tile 32), 1024 thr / 16 waves, 128 phases (16h x 8 s-tiles of 128).
// K and V^T fragments are per-lane contiguous 16B loads -> read straight from L1/L2
// (K/V for this b = 4MB, resident in this XCD's L2; b == XCD via blockIdx&7).
// Phase: QK (kf direct) -> pstash stores -> lgkm(0)+bar -> PV (af from pstash, vf direct).
// QK(p+1) writes pstash region st+1 (disjoint from PV(p)'s region st) -> no 2nd barrier.
__global__ __launch_bounds__(1024)
void attn_kernel(const uint16_t* __restrict__ Qh, const uint16_t* __restrict__ Kh,
                 const uint16_t* __restrict__ Vh, const int* __restrict__ hdr,
                 uint16_t* __restrict__ AP, uint16_t* __restrict__ Wm) {
  __shared__ __align__(16) uint16_t pstash[32][1024]; // chunk low3 ^= (t&7)
  __shared__ float pvx[2][32][68];

  const int tid = threadIdx.x, lane = tid & 63, w = tid >> 6;
  const int g = lane >> 4, cc = lane & 15;
  const int wt = w >> 3, ws = w & 7;       // QK roles
  const int dq = (w >> 1) & 3, ks = w & 1; // PV roles (wt shared)
  const int b = blockIdx.x & 7, tt = blockIdx.x >> 3;
  const int t0 = tt * 32;
  const int len = hdr[1 + b];
  const int tme = tid >> 5, s5 = tid & 31;

  float wmean[32];
#pragma unroll
  for (int j = 0; j < 32; ++j) wmean[j] = 0.f;

  for (int h = 0; h < 16; ++h) {
    const uint16_t* Qb = Qh + ((size_t)(b * 16 + h) << 16) + (((size_t)(t0 + wt * 16 + cc)) << 6);
    const uint16_t* Kb = Kh + ((size_t)(b * 16 + h) << 16);
    const uint16_t* Vt = Vh + ((size_t)(b * 16 + h) << 16);
    const bf16x8 qf0 = *(const bf16x8*)(Qb + g * 8);
    const bf16x8 qf1 = *(const bf16x8*)(Qb + 32 + g * 8);
    f32x4 pv = (f32x4){0.f, 0.f, 0.f, 0.f};
    for (int st = 0; st < 8; ++st) {
      // ---- QK: wave (wt,ws) 16t x 16s; K frags direct from L2 ----
      {
        const int row = ws * 16 + cc;  // s within tile
        const uint16_t* kp = Kb + (size_t)(st * 128 + row) * 64 + g * 8;
        const bf16x8 kf0 = *(const bf16x8*)kp;
        const bf16x8 kf1 = *(const bf16x8*)(kp + 32);
        f32x4 a = (f32x4){0.f, 0.f, 0.f, 0.f};
        a = __builtin_amdgcn_mfma_f32_16x16x32_bf16(qf0, kf0, a, 0, 0, 0);
        a = __builtin_amdgcn_mfma_f32_16x16x32_bf16(qf1, kf1, a, 0, 0, 0);
        const int s = st * 128 + row;
        const bool msk = (s >= len);
        float vv0 = msk ? 0.f : __expf(a[0]);
        float vv1 = msk ? 0.f : __expf(a[1]);
        float vv2 = msk ? 0.f : __expf(a[2]);
        float vv3 = msk ? 0.f : __expf(a[3]);
        uint32_t pk01, pk23;
        asm("v_cvt_pk_bf16_f32 %0, %1, %2" : "=v"(pk01) : "v"(vv0), "v"(vv1));
        asm("v_cvt_pk_bf16_f32 %0, %1, %2" : "=v"(pk23) : "v"(vv2), "v"(vv3));
        const uint16_t pb[4] = {(uint16_t)pk01, (uint16_t)(pk01 >> 16),
                                (uint16_t)pk23, (uint16_t)(pk23 >> 16)};
        const int cbase = st * 16 + ws * 2 + (cc >> 3);
#pragma unroll
        for (int r = 0; r < 4; ++r) {
          const int tl = wt * 16 + g * 4 + r;
          const int cs = (cbase & ~7) | ((cbase ^ tl) & 7);
          pstash[tl][(cs << 3) + (cc & 7)] = pb[r];
        }
      }
      // bar: pstash region st visible to all waves
      asm volatile("s_waitcnt lgkmcnt(0)" ::: "memory");
      __builtin_amdgcn_sched_barrier(0);
      __builtin_amdgcn_s_barrier();
      // ---- PV: wave (wt,dq,ks) 16t x 16d, k = ks-half (64 s); V frags direct from L2 ----
      {
        const int tr = wt * 16 + cc;
        const uint16_t* vp = Vt + (size_t)(dq * 16 + cc) * 1024 + st * 128 + ks * 64 + g * 8;
#pragma unroll
        for (int kk = 0; kk < 2; ++kk) {
          const int ca = st * 16 + ks * 8 + kk * 4 + g;
          const int ca2 = (ca & ~7) | ((ca ^ tr) & 7);
          const bf16x8 af = *(const bf16x8*)&pstash[tr][ca2 << 3];
          const bf16x8 vf = *(const bf16x8*)(vp + kk * 32);
          pv = __builtin_amdgcn_mfma_f32_16x16x32_bf16(af, vf, pv, 0, 0, 0);
        }
      }
      // no second barrier: next phase's QK writes region st+1 (disjoint)
    }
    // ---- head end ----
#pragma unroll
    for (int r = 0; r < 4; ++r)
      pvx[ks][wt * 16 + g * 4 + r][dq * 16 + cc] = pv[r];
    float winv;
    {
      uint32_t p4[16];
#pragma unroll
      for (int q = 0; q < 4; ++q) {
        const int c = s5 + 32 * q;  // bank-even
        const int c2 = (c & ~7) | ((c ^ tme) & 7);
        *(u32x4*)&p4[q * 4] = *(const u32x4*)&pstash[tme][c2 << 3];
      }
      float sm = 0.f;
#pragma unroll
      for (int j = 0; j < 16; ++j) {
        sm += b2f((uint16_t)(p4[j] & 0xffffu));
        sm += b2f((uint16_t)(p4[j] >> 16));
      }
#pragma unroll
      for (int m = 16; m >= 1; m >>= 1) sm += __shfl_xor(sm, m, 64);
      winv = 1.f / sm;
#pragma unroll
      for (int j = 0; j < 16; ++j) {
        wmean[2 * j] += b2f((uint16_t)(p4[j] & 0xffffu)) * winv;
        wmean[2 * j + 1] += b2f((uint16_t)(p4[j] >> 16)) * winv;
      }
    }
    asm volatile("s_waitcnt lgkmcnt(0)" ::: "memory");
    __builtin_amdgcn_sched_barrier(0);
    __builtin_amdgcn_s_barrier();  // pvx visible; pstash reads done (next head reuses)
    {
      const int d0 = s5 * 2;
      const float v0 = (pvx[0][tme][d0] + pvx[1][tme][d0]) * winv;
      const float v1 = (pvx[0][tme][d0 + 1] + pvx[1][tme][d0 + 1]) * winv;
      const uint32_t pk = (uint32_t)f2b(v0) | ((uint32_t)f2b(v1) << 16);
      *(uint32_t*)(AP + ((((size_t)(t0 + tme)) * 8 + b) << 10) + h * 64 + d0) = pk;
    }
  }

  // ---- Wm output: wmean[q*8+e] <-> s = s5*8 + q*256 + e; 512B contiguous per q ----
  {
    uint16_t* dst = Wm + (((size_t)(b * 1024 + t0 + tme)) << 10);
#pragma unroll
    for (int q = 0; q < 4; ++q) {
      uint16_t ob[8];
#pragma unroll
      for (int e = 0; e < 8; ++e) ob[e] = f2b(wmean[q * 8 + e] * 0.0625f);
      *(u32x4*)(dst + q * 256 + s5 * 8) = *(const u32x4*)ob;
    }
  }
}

// ---------------- weights transpose: Wm[b][t][s] bf16 -> out (S,T,B) ----------------
__global__ __launch_bounds__(256)
void wtrans_kernel(const uint16_t* __restrict__ Wm, const int* __restrict__ hdr,
                   void* __restrict__ outBase) {
  __shared__ uint16_t lt[8][32][68];
  const int tid = threadIdx.x;
  const int s0 = blockIdx.x * 64, t0 = blockIdx.y * 32;
  const int isf = hdr[0];
  const int rr = tid >> 4;
  const int sc = (tid & 15) * 4;
#pragma unroll
  for (int p = 0; p < 16; ++p) {
    const int row = p * 16 + rr;
    const int b = row >> 5, t = row & 31;
    const uint64_t v = *(const uint64_t*)(Wm + (((size_t)(b * 1024 + t0 + t)) << 10) + s0 + sc);
    *(uint64_t*)&lt[b][t][sc] = v;
  }
  __syncthreads();
#pragma unroll
  for (int p = 0; p < 8; ++p) {
    const int pair = p * 256 + tid;
    const int t = pair & 31, s = pair >> 5;
    const size_t o = 8388608 + ((size_t)(s0 + s) * 1024 + (t0 + t)) * 8;
    if (isf) {
      f32x4 v0, v1;
#pragma unroll
      for (int b = 0; b < 4; ++b) v0[b] = b2f(lt[b][t][s]);
#pragma unroll
      for (int b = 0; b < 4; ++b) v1[b] = b2f(lt[b + 4][t][s]);
      *(f32x4*)((float*)outBase + o) = v0;
      *(f32x4*)((float*)outBase + o + 4) = v1;
    } else {
      u32x4 v;
#pragma unroll
      for (int q = 0; q < 4; ++q)
        v[q] = (uint32_t)lt[2 * q][t][s] | ((uint32_t)lt[2 * q + 1][t][s] << 16);
      *(u32x4*)((uint16_t*)outBase + o) = v;
    }
  }
}

__global__ void fill_pattern(uint32_t* p, size_t n) {
  size_t i = (size_t)blockIdx.x * 256 + threadIdx.x;
  const size_t stride = (size_t)gridDim.x * 256;
  for (; i < n; i += stride) p[i] = 0x3f3f3f3fu;
}

extern "C" void kernel_launch(void* const* d_in, const int* in_sizes, int n_in,
                              void* d_out, int out_size, void* d_ws, size_t ws_size,
                              hipStream_t stream) {
  char* ws = (char*)d_ws;
  int* hdr = (int*)ws;
  float* bias = (float*)(ws + 4096);
  uint16_t* Q = (uint16_t*)(ws + (1u << 20));
  uint16_t* K = Q + 8388608;
  uint16_t* V = K + 8388608;
  uint16_t* AP = V + 8388608;
  uint16_t* Wm = AP + 8388608;
  uint16_t* dec_b = AP;
  uint16_t* src_b = Wm;
  const size_t needBase = (1ull << 20) + 5ull * 16777216ull;
  const size_t needFull = needBase + 8ull * 1048576ull;
  uint16_t* Wb = (uint16_t*)(ws + needBase);
  const int useConvW = (ws_size >= needFull) ? 1 : 0;
  if (ws_size < needBase) {
    fill_pattern<<<1024, 256, 0, stream>>>((uint32_t*)d_out, (size_t)out_size / 2);
    return;
  }

  detect_kernel<<<1, 256, 0, stream>>>(d_in[3], d_in[2], d_in[4], d_in[6], d_in[8], d_in[10], hdr, bias);

  convert_kernel<<<4096, 256, 0, stream>>>(d_in[0], d_in[1], d_in[3], d_in[5], d_in[7], d_in[9],
                                           dec_b, src_b, Wb, hdr, useConvW);

  const void* Wq = useConvW ? (const void*)(Wb + 0 * 1048576) : (const void*)d_in[3];
  const void* Wk = useConvW ? (const void*)(Wb + 1 * 1048576) : (const void*)d_in[5];
  const void* Wv = useConvW ? (const void*)(Wb + 2 * 1048576) : (const void*)d_in[7];
  const void* Wo = useConvW ? (const void*)(Wb + 3 * 1048576) : (const void*)d_in[9];

  gemm_qkv<<<dim3(64, 24), 256, 0, stream>>>(dec_b, src_b, Wq, Wk, Wv, bias, hdr, Q, K, V, useConvW);

  attn_kernel<<<256, 1024, 0, stream>>>(Q, K, V, hdr, AP, Wm);

  wtrans_kernel<<<dim3(16, 32), 256, 0, stream>>>(Wm, hdr, d_out);

  gemm_bt<MO><<<dim3(64, 8), 256, 0, stream>>>(AP, Wo, bias + 3072, hdr, d_out, 1.f, useConvW);
}

// Round 17
// 291.901 us; speedup vs baseline: 1.5982x; 1.5982x over previous
//
#include <hip/hip_runtime.h>
#include <stdint.h>
#include <stddef.h>

typedef __attribute__((ext_vector_type(8))) short bf16x8;
typedef __attribute__((ext_vector_type(4))) float f32x4;
typedef __attribute__((ext_vector_type(4))) uint32_t u32x4;

#define DEVINL static __device__ __forceinline__

DEVINL float b2f(uint16_t u) {
  uint32_t x = ((uint32_t)u) << 16;
  float f;
  __builtin_memcpy(&f, &x, 4);
  return f;
}

DEVINL uint16_t f2b(float f) {
  uint32_t u;
  __builtin_memcpy(&u, &f, 4);
  return (uint16_t)((u + 0x7fffu + ((u >> 16) & 1u)) >> 16);
}

DEVINL void gload16(const void* gsrc, void* ldst) {
  __builtin_amdgcn_global_load_lds(
      (const __attribute__((address_space(1))) void*)gsrc,
      (__attribute__((address_space(3))) void*)ldst, 16, 0, 0);
}

// ---------------- runtime dtype/mask detection ----------------
__global__ void detect_kernel(const void* __restrict__ wq, const void* __restrict__ mask,
                              const void* __restrict__ bq, const void* __restrict__ bk,
                              const void* __restrict__ bv, const void* __restrict__ bo,
                              int* __restrict__ hdr, float* __restrict__ bias) {
  __shared__ int sflag, smask32, slen[8];
  const int tid = threadIdx.x;
  if (tid == 0) { sflag = 0; smask32 = 0; }
  if (tid < 8) slen[tid] = 0;
  __syncthreads();
  const uint16_t* w16 = (const uint16_t*)wq;
  int f = 0;
  for (int i = tid; i < 4096; i += 256) {
    uint16_t u = w16[i];
    uint32_t e = (u >> 7) & 0xFFu;
    if (fabsf(b2f(u)) > 0.25f || e == 0xFFu) f = 1;
  }
  if (f) atomicOr(&sflag, 1);
  const uint8_t* mb = (const uint8_t*)mask;
  int m32 = 0;
  for (int i = tid; i < 8191; i += 256) {
    if ((i & 1023) != 1023 && mb[i] != 0 && mb[i + 1] == 0) m32 = 1;
  }
  if (m32) atomicOr(&smask32, 1);
  __syncthreads();
  if (smask32) {
    const int* mi = (const int*)mask;
    for (int i = tid; i < 8192; i += 256) { if (mi[i] == 0) atomicAdd(&slen[i >> 10], 1); }
  } else {
    for (int i = tid; i < 8192; i += 256) { if (mb[i] == 0) atomicAdd(&slen[i >> 10], 1); }
  }
  __syncthreads();
  if (tid == 0) hdr[0] = sflag;
  if (tid < 8) hdr[1 + tid] = slen[tid];
  const void* bs[4] = {bq, bk, bv, bo};
  for (int j = 0; j < 4; ++j) {
    for (int i = tid; i < 1024; i += 256) {
      float v = sflag ? ((const float*)bs[j])[i] : b2f(((const uint16_t*)bs[j])[i]);
      bias[j * 1024 + i] = v;
    }
  }
}

// ---------------- fp32 -> bf16 conversion pass (or bf16 copy) ----------------
__global__ __launch_bounds__(256)
void convert_kernel(const void* __restrict__ s0, const void* __restrict__ s1,
                    const void* __restrict__ s2, const void* __restrict__ s3,
                    const void* __restrict__ s4, const void* __restrict__ s5,
                    uint16_t* __restrict__ d0, uint16_t* __restrict__ d1,
                    uint16_t* __restrict__ d2, const int* __restrict__ hdr, int doW) {
  const int isf = hdr[0];
  const size_t n01 = 1048576;
  const size_t nw = 131072;
  const size_t total = doW ? (2 * n01 + 4 * nw) : (2 * n01);
  size_t gid = (size_t)blockIdx.x * 256 + threadIdx.x;
  const size_t stride = (size_t)gridDim.x * 256;
  for (; gid < total; gid += stride) {
    const void* sp;
    uint16_t* dp;
    size_t off;
    if (gid < n01) { sp = s0; dp = d0; off = gid; }
    else if (gid < 2 * n01) { sp = s1; dp = d1; off = gid - n01; }
    else {
      const size_t w = (gid - 2 * n01) >> 17;
      off = (gid - 2 * n01) & (nw - 1);
      sp = (w == 0) ? s2 : (w == 1) ? s3 : (w == 2) ? s4 : s5;
      dp = d2 + w * 1048576;
    }
    if (isf) {
      const float* fp = (const float*)sp + off * 8;
      const f32x4 a = *(const f32x4*)fp;
      const f32x4 c = *(const f32x4*)(fp + 4);
      u32x4 r;
      r[0] = (uint32_t)f2b(a[0]) | ((uint32_t)f2b(a[1]) << 16);
      r[1] = (uint32_t)f2b(a[2]) | ((uint32_t)f2b(a[3]) << 16);
      r[2] = (uint32_t)f2b(c[0]) | ((uint32_t)f2b(c[1]) << 16);
      r[3] = (uint32_t)f2b(c[2]) | ((uint32_t)f2b(c[3]) << 16);
      *(u32x4*)(dp + off * 8) = r;
    } else {
      *(u32x4*)(dp + off * 8) = *(const u32x4*)((const uint16_t*)sp + off * 8);
    }
  }
}

// ---------------- GEMM core pieces ----------------
enum { MQ = 0, MK = 1, MV = 2, MO = 3 };

DEVINL u32x4 load8w(const void* __restrict__ src, bool f32, size_t eoff) {
  if (!f32) {
    return *(const u32x4*)((const uint16_t*)src + eoff);
  }
  const float* p = (const float*)src + eoff;
  const f32x4 a = *(const f32x4*)p;
  const f32x4 c = *(const f32x4*)(p + 4);
  u32x4 r;
  r[0] = (uint32_t)f2b(a[0]) | ((uint32_t)f2b(a[1]) << 16);
  r[1] = (uint32_t)f2b(a[2]) | ((uint32_t)f2b(a[3]) << 16);
  r[2] = (uint32_t)f2b(c[0]) | ((uint32_t)f2b(c[1]) << 16);
  r[3] = (uint32_t)f2b(c[2]) | ((uint32_t)f2b(c[3]) << 16);
  return r;
}

// ---------------- merged Q/K/V GEMM (single-buffer, XCD-swizzled) ----------------
// grid 1536 1D. Linear id L remapped: bm = (L%8)*8 + (L/8)%8, panel y = L/64.
// Each XCD (L%8) owns a contiguous 8-bm A slice (2MB, L2-resident) x all 24 W panels;
// consecutive blocks within an XCD share one W panel (256KB) -> working set < 4MB L2.
__global__ __launch_bounds__(256)
void gemm_qkv(const uint16_t* __restrict__ dec_b, const uint16_t* __restrict__ src_b,
              const void* __restrict__ Wq, const void* __restrict__ Wk,
              const void* __restrict__ Wv, const float* __restrict__ bias,
              const int* __restrict__ hdr, uint16_t* __restrict__ Q,
              uint16_t* __restrict__ K, uint16_t* __restrict__ V, int wIsBf16) {
  __shared__ __align__(16) uint16_t lA[8192];
  __shared__ __align__(16) uint16_t lB[8192];
  const int tid = threadIdx.x, lane = tid & 63, wave = tid >> 6;
  const int L = blockIdx.x;
  const int bm = (L & 7) * 8 + ((L >> 3) & 7);
  const int y = L >> 6;
  const int grp = y >> 3, bn = y & 7;
  const int isf = hdr[0];
  const bool wF32 = (wIsBf16 == 0) && (isf != 0);
  const uint16_t* Ab = (grp == 0) ? dec_b : src_b;
  const void* Wr = (grp == 0) ? Wq : (grp == 1) ? Wk : Wv;
  const float* bs = bias + grp * 1024;
  const float scale = (grp == 0) ? 0.125f : 1.f;
  const int wm = wave >> 1, wn = wave & 1;
  const int g = lane >> 4, cc = lane & 15;
  const int lr = lane >> 3, lc = lane & 7;
  const int scc = (lc ^ lr) * 8;

  f32x4 acc[4][4];
#pragma unroll
  for (int i = 0; i < 4; ++i)
#pragma unroll
    for (int j = 0; j < 4; ++j) acc[i][j] = (f32x4){0.f, 0.f, 0.f, 0.f};

  for (int kt = 0; kt < 16; ++kt) {
    __syncthreads();  // WAR
#pragma unroll
    for (int q = 0; q < 4; ++q) {
      const int j = wave * 4 + q;
      gload16(Ab + (size_t)(bm * 128 + j * 8 + lr) * 1024 + kt * 64 + scc, &lA[j * 512]);
    }
    if (!wF32) {
#pragma unroll
      for (int q = 0; q < 4; ++q) {
        const int j = wave * 4 + q;
        gload16((const uint16_t*)Wr + (size_t)(bn * 128 + j * 8 + lr) * 1024 + kt * 64 + scc, &lB[j * 512]);
      }
    } else {
#pragma unroll
      for (int q = 0; q < 4; ++q) {
        const int j = wave * 4 + q;
        const u32x4 rv = load8w(Wr, true, (size_t)(bn * 128 + j * 8 + lr) * 1024 + kt * 64 + lc * 8);
        *(u32x4*)&lB[j * 512 + lr * 64 + ((lc ^ lr) * 8)] = rv;
      }
    }
    __syncthreads();  // RAW
#pragma unroll
    for (int kk = 0; kk < 2; ++kk) {
      bf16x8 af[4], bfr[4];
#pragma unroll
      for (int mi = 0; mi < 4; ++mi) {
        const int row = wm * 64 + mi * 16 + cc;
        af[mi] = *(const bf16x8*)&lA[row * 64 + (((kk * 4 + g) ^ (cc & 7)) << 3)];
      }
#pragma unroll
      for (int ni = 0; ni < 4; ++ni) {
        const int row = wn * 64 + ni * 16 + cc;
        bfr[ni] = *(const bf16x8*)&lB[row * 64 + (((kk * 4 + g) ^ (cc & 7)) << 3)];
      }
#pragma unroll
      for (int mi = 0; mi < 4; ++mi)
#pragma unroll
        for (int ni = 0; ni < 4; ++ni)
          acc[mi][ni] = __builtin_amdgcn_mfma_f32_16x16x32_bf16(af[mi], bfr[ni], acc[mi][ni], 0, 0, 0);
    }
  }
#pragma unroll
  for (int mi = 0; mi < 4; ++mi) {
#pragma unroll
    for (int ni = 0; ni < 4; ++ni) {
      const int col = bn * 128 + wn * 64 + ni * 16 + cc;
      const float bv = bs[col];
      const int r0 = bm * 128 + wm * 64 + mi * 16 + g * 4;
#pragma unroll
      for (int r = 0; r < 4; ++r) {
        const int row = r0 + r;
        const float v = (acc[mi][ni][r] + bv) * scale;
        if (grp == 0) {        // rows = (b,t); Q[b][h][t][d]
          const int b = row >> 10, t = row & 1023, h = col >> 6, d = col & 63;
          Q[(((size_t)(b * 16 + h) << 10) + t) * 64 + d] = f2b(v);
        } else if (grp == 1) { // rows = (s,b); K[b][h][s][d]
          const int s = row >> 3, b = row & 7, h = col >> 6, d = col & 63;
          K[(((size_t)(b * 16 + h) << 10) + s) * 64 + d] = f2b(v);
        } else {               // V^T[b][h][d][s]
          const int s = row >> 3, b = row & 7, h = col >> 6, d = col & 63;
          V[(((size_t)(b * 16 + h) << 6) + d) * 1024 + s] = f2b(v);
        }
      }
    }
  }
}

// ---------------- output GEMM (single-buffer, XCD-swizzled) ----------------
// grid 512 1D: bm = (L%8)*8 + (L/8)%8, bn = L/64. Per-XCD: 2MB A slice + 2MB Wo.
template <int MODE>
__global__ __launch_bounds__(256)
void gemm_bt(const uint16_t* __restrict__ Ab, const void* __restrict__ Wr,
             const float* __restrict__ bias, const int* __restrict__ hdr,
             void* __restrict__ outp, float scale, int wIsBf16) {
  __shared__ __align__(16) uint16_t lA[8192];
  __shared__ __align__(16) uint16_t lB[8192];
  const int tid = threadIdx.x, lane = tid & 63, wave = tid >> 6;
  const int L = blockIdx.x;
  const int bm = (L & 7) * 8 + ((L >> 3) & 7);
  const int bn = L >> 6;
  const int isf = hdr[0];
  const bool wF32 = (wIsBf16 == 0) && (isf != 0);
  const int wm = wave >> 1, wn = wave & 1;
  const int g = lane >> 4, cc = lane & 15;
  const int lr = lane >> 3, lc = lane & 7;
  const int scc = (lc ^ lr) * 8;

  f32x4 acc[4][4];
#pragma unroll
  for (int i = 0; i < 4; ++i)
#pragma unroll
    for (int j = 0; j < 4; ++j) acc[i][j] = (f32x4){0.f, 0.f, 0.f, 0.f};

  for (int kt = 0; kt < 16; ++kt) {
    __syncthreads();
#pragma unroll
    for (int q = 0; q < 4; ++q) {
      const int j = wave * 4 + q;
      gload16(Ab + (size_t)(bm * 128 + j * 8 + lr) * 1024 + kt * 64 + scc, &lA[j * 512]);
    }
    if (!wF32) {
#pragma unroll
      for (int q = 0; q < 4; ++q) {
        const int j = wave * 4 + q;
        gload16((const uint16_t*)Wr + (size_t)(bn * 128 + j * 8 + lr) * 1024 + kt * 64 + scc, &lB[j * 512]);
      }
    } else {
#pragma unroll
      for (int q = 0; q < 4; ++q) {
        const int j = wave * 4 + q;
        const u32x4 rv = load8w(Wr, true, (size_t)(bn * 128 + j * 8 + lr) * 1024 + kt * 64 + lc * 8);
        *(u32x4*)&lB[j * 512 + lr * 64 + ((lc ^ lr) * 8)] = rv;
      }
    }
    __syncthreads();
#pragma unroll
    for (int kk = 0; kk < 2; ++kk) {
      bf16x8 af[4], bfr[4];
#pragma unroll
      for (int mi = 0; mi < 4; ++mi) {
        const int row = wm * 64 + mi * 16 + cc;
        af[mi] = *(const bf16x8*)&lA[row * 64 + (((kk * 4 + g) ^ (cc & 7)) << 3)];
      }
#pragma unroll
      for (int ni = 0; ni < 4; ++ni) {
        const int row = wn * 64 + ni * 16 + cc;
        bfr[ni] = *(const bf16x8*)&lB[row * 64 + (((kk * 4 + g) ^ (cc & 7)) << 3)];
      }
#pragma unroll
      for (int mi = 0; mi < 4; ++mi)
#pragma unroll
        for (int ni = 0; ni < 4; ++ni)
          acc[mi][ni] = __builtin_amdgcn_mfma_f32_16x16x32_bf16(af[mi], bfr[ni], acc[mi][ni], 0, 0, 0);
    }
  }
#pragma unroll
  for (int mi = 0; mi < 4; ++mi) {
#pragma unroll
    for (int ni = 0; ni < 4; ++ni) {
      const int col = bn * 128 + wn * 64 + ni * 16 + cc;
      const float bv = bias[col];
      const int r0 = bm * 128 + wm * 64 + mi * 16 + g * 4;
#pragma unroll
      for (int r = 0; r < 4; ++r) {
        const int row = r0 + r;
        const float v = (acc[mi][ni][r] + bv) * scale;
        const size_t o = (size_t)row * 1024 + col;
        if (isf) ((float*)outp)[o] = v;
        else ((uint16_t*)outp)[o] = f2b(v);
      }
    }
  }
}

// ---------------- fused attention (v14: v11 pipeline + cvt_pk store) ----------------
__global__ __launch_bounds__(1024)
void attn_kernel(const uint16_t* __restrict__ Qh, const uint16_t* __restrict__ Kh,
                 const uint16_t* __restrict__ Vh, const int* __restrict__ hdr,
                 uint16_t* __restrict__ AP, uint16_t* __restrict__ Wm) {
  __shared__ __align__(16) uint16_t kbuf[2][8192];    // [s128][d64], chunk c ^= (s&7)
  __shared__ __align__(16) uint16_t vbuf[2][8192];    // [d64][s128], chunk low3 ^= (d&7)
  __shared__ __align__(16) uint16_t pstash[32][1024]; // chunk low3 ^= (t&7)
  __shared__ float pvx[2][32][68];

  const int tid = threadIdx.x, lane = tid & 63, w = tid >> 6;
  const int g = lane >> 4, cc = lane & 15;
  const int wt = w >> 3, ws = w & 7;       // QK roles
  const int dq = (w >> 1) & 3, ks = w & 1; // PV roles (wt shared)
  const int b = blockIdx.x & 7, tt = blockIdx.x >> 3;
  const int t0 = tt * 32;
  const int len = hdr[1 + b];
  const int tme = tid >> 5, s5 = tid & 31;

  auto stage = [&](int p, int buf) {  // p = h*8+st; 2 VMEM per thread
    const int hh = p >> 3, st = p & 7;
    const uint16_t* Kb = Kh + ((size_t)(b * 16 + hh) << 16);
    const uint16_t* Vt = Vh + ((size_t)(b * 16 + hh) << 16);
    {
      const int row = tid >> 3;
      const int c = (tid & 7) ^ (row & 7);
      gload16(Kb + (st * 128 + row) * 64 + c * 8, &kbuf[buf][w * 512]);
    }
    {
      const int d = tid >> 4;
      const int c = tid & 15;
      const int cg = (c & 8) | ((c ^ (d & 7)) & 7);
      gload16(Vt + d * 1024 + st * 128 + cg * 8, &vbuf[buf][w * 512]);
    }
  };

  stage(0, 0);

  float wmean[32];
#pragma unroll
  for (int j = 0; j < 32; ++j) wmean[j] = 0.f;

  for (int h = 0; h < 16; ++h) {
    const uint16_t* Qb = Qh + ((size_t)(b * 16 + h) << 16) + (((size_t)(t0 + wt * 16 + cc)) << 6);
    const bf16x8 qf0 = *(const bf16x8*)(Qb + g * 8);
    const bf16x8 qf1 = *(const bf16x8*)(Qb + 32 + g * 8);
    f32x4 pv = (f32x4){0.f, 0.f, 0.f, 0.f};
    for (int st = 0; st < 8; ++st) {
      const int p = h * 8 + st;
      const int cur = p & 1;
      asm volatile("s_waitcnt vmcnt(0)" ::: "memory");
      __builtin_amdgcn_sched_barrier(0);
      __builtin_amdgcn_s_barrier();
      if (p + 1 < 128) stage(p + 1, cur ^ 1);
      // QK: wave (wt,ws) 16t x 16s
      {
        const int row = ws * 16 + cc;
        f32x4 a = (f32x4){0.f, 0.f, 0.f, 0.f};
#pragma unroll
        for (int kk = 0; kk < 2; ++kk) {
          const bf16x8 kf = *(const bf16x8*)&kbuf[cur][row * 64 + (((kk * 4 + g) ^ (cc & 7)) << 3)];
          a = __builtin_amdgcn_mfma_f32_16x16x32_bf16(kk ? qf1 : qf0, kf, a, 0, 0, 0);
        }
        const int s = st * 128 + row;
        const bool msk = (s >= len);
        float vv0 = msk ? 0.f : __expf(a[0]);
        float vv1 = msk ? 0.f : __expf(a[1]);
        float vv2 = msk ? 0.f : __expf(a[2]);
        float vv3 = msk ? 0.f : __expf(a[3]);
        uint32_t pk01, pk23;
        asm("v_cvt_pk_bf16_f32 %0, %1, %2" : "=v"(pk01) : "v"(vv0), "v"(vv1));
        asm("v_cvt_pk_bf16_f32 %0, %1, %2" : "=v"(pk23) : "v"(vv2), "v"(vv3));
        const uint16_t pb[4] = {(uint16_t)pk01, (uint16_t)(pk01 >> 16),
                                (uint16_t)pk23, (uint16_t)(pk23 >> 16)};
        const int cbase = st * 16 + ws * 2 + (cc >> 3);
#pragma unroll
        for (int r = 0; r < 4; ++r) {
          const int tl = wt * 16 + g * 4 + r;
          const int cs = (cbase & ~7) | ((cbase ^ tl) & 7);
          pstash[tl][(cs << 3) + (cc & 7)] = pb[r];
        }
      }
      asm volatile("s_waitcnt lgkmcnt(0)" ::: "memory");
      __builtin_amdgcn_sched_barrier(0);
      __builtin_amdgcn_s_barrier();
      // PV: wave (wt,dq,ks) 16t x 16d, k = ks-half (64 s)
      {
        const int tr = wt * 16 + cc;
#pragma unroll
        for (int kk = 0; kk < 2; ++kk) {
          const int ca = st * 16 + ks * 8 + kk * 4 + g;
          const int ca2 = (ca & ~7) | ((ca ^ tr) & 7);
          const bf16x8 af = *(const bf16x8*)&pstash[tr][ca2 << 3];
          const int cv = ks * 8 + kk * 4 + g;
          const int cv2 = (cv & 8) | ((cv ^ (cc & 7)) & 7);
          const bf16x8 vf = *(const bf16x8*)&vbuf[cur][(dq * 16 + cc) * 128 + (cv2 << 3)];
          pv = __builtin_amdgcn_mfma_f32_16x16x32_bf16(af, vf, pv, 0, 0, 0);
        }
      }
    }
    // ---- head end ----
#pragma unroll
    for (int r = 0; r < 4; ++r)
      pvx[ks][wt * 16 + g * 4 + r][dq * 16 + cc] = pv[r];
    float winv;
    {
      uint32_t p4[16];
#pragma unroll
      for (int q = 0; q < 4; ++q) {
        const int c = s5 + 32 * q;
        const int c2 = (c & ~7) | ((c ^ tme) & 7);
        *(u32x4*)&p4[q * 4] = *(const u32x4*)&pstash[tme][c2 << 3];
      }
      float sm = 0.f;
#pragma unroll
      for (int j = 0; j < 16; ++j) {
        sm += b2f((uint16_t)(p4[j] & 0xffffu));
        sm += b2f((uint16_t)(p4[j] >> 16));
      }
#pragma unroll
      for (int m = 16; m >= 1; m >>= 1) sm += __shfl_xor(sm, m, 64);
      winv = 1.f / sm;
#pragma unroll
      for (int j = 0; j < 16; ++j) {
        wmean[2 * j] += b2f((uint16_t)(p4[j] & 0xffffu)) * winv;
        wmean[2 * j + 1] += b2f((uint16_t)(p4[j] >> 16)) * winv;
      }
    }
    asm volatile("s_waitcnt lgkmcnt(0)" ::: "memory");
    __builtin_amdgcn_sched_barrier(0);
    __builtin_amdgcn_s_barrier();
    {
      const int d0 = s5 * 2;
      const float v0 = (pvx[0][tme][d0] + pvx[1][tme][d0]) * winv;
      const float v1 = (pvx[0][tme][d0 + 1] + pvx[1][tme][d0 + 1]) * winv;
      const uint32_t pk = (uint32_t)f2b(v0) | ((uint32_t)f2b(v1) << 16);
      *(uint32_t*)(AP + ((((size_t)(t0 + tme)) * 8 + b) << 10) + h * 64 + d0) = pk;
    }
  }

  // ---- Wm output ----
  {
    uint16_t* dst = Wm + (((size_t)(b * 1024 + t0 + tme)) << 10);
#pragma unroll
    for (int q = 0; q < 4; ++q) {
      uint16_t ob[8];
#pragma unroll
      for (int e = 0; e < 8; ++e) ob[e] = f2b(wmean[q * 8 + e] * 0.0625f);
      *(u32x4*)(dst + q * 256 + s5 * 8) = *(const u32x4*)ob;
    }
  }
}

// ---------------- weights transpose: Wm[b][t][s] bf16 -> out (S,T,B) ----------------
__global__ __launch_bounds__(256)
void wtrans_kernel(const uint16_t* __restrict__ Wm, const int* __restrict__ hdr,
                   void* __restrict__ outBase) {
  __shared__ uint16_t lt[8][32][68];
  const int tid = threadIdx.x;
  const int s0 = blockIdx.x * 64, t0 = blockIdx.y * 32;
  const int isf = hdr[0];
  const int rr = tid >> 4;
  const int sc = (tid & 15) * 4;
#pragma unroll
  for (int p = 0; p < 16; ++p) {
    const int row = p * 16 + rr;
    const int b = row >> 5, t = row & 31;
    const uint64_t v = *(const uint64_t*)(Wm + (((size_t)(b * 1024 + t0 + t)) << 10) + s0 + sc);
    *(uint64_t*)&lt[b][t][sc] = v;
  }
  __syncthreads();
#pragma unroll
  for (int p = 0; p < 8; ++p) {
    const int pair = p * 256 + tid;
    const int t = pair & 31, s = pair >> 5;
    const size_t o = 8388608 + ((size_t)(s0 + s) * 1024 + (t0 + t)) * 8;
    if (isf) {
      f32x4 v0, v1;
#pragma unroll
      for (int b = 0; b < 4; ++b) v0[b] = b2f(lt[b][t][s]);
#pragma unroll
      for (int b = 0; b < 4; ++b) v1[b] = b2f(lt[b + 4][t][s]);
      *(f32x4*)((float*)outBase + o) = v0;
      *(f32x4*)((float*)outBase + o + 4) = v1;
    } else {
      u32x4 v;
#pragma unroll
      for (int q = 0; q < 4; ++q)
        v[q] = (uint32_t)lt[2 * q][t][s] | ((uint32_t)lt[2 * q + 1][t][s] << 16);
      *(u32x4*)((uint16_t*)outBase + o) = v;
    }
  }
}

__global__ void fill_pattern(uint32_t* p, size_t n) {
  size_t i = (size_t)blockIdx.x * 256 + threadIdx.x;
  const size_t stride = (size_t)gridDim.x * 256;
  for (; i < n; i += stride) p[i] = 0x3f3f3f3fu;
}

extern "C" void kernel_launch(void* const* d_in, const int* in_sizes, int n_in,
                              void* d_out, int out_size, void* d_ws, size_t ws_size,
                              hipStream_t stream) {
  char* ws = (char*)d_ws;
  int* hdr = (int*)ws;
  float* bias = (float*)(ws + 4096);
  uint16_t* Q = (uint16_t*)(ws + (1u << 20));
  uint16_t* K = Q + 8388608;
  uint16_t* V = K + 8388608;
  uint16_t* AP = V + 8388608;
  uint16_t* Wm = AP + 8388608;
  uint16_t* dec_b = AP;
  uint16_t* src_b = Wm;
  const size_t needBase = (1ull << 20) + 5ull * 16777216ull;
  const size_t needFull = needBase + 8ull * 1048576ull;
  uint16_t* Wb = (uint16_t*)(ws + needBase);
  const int useConvW = (ws_size >= needFull) ? 1 : 0;
  if (ws_size < needBase) {
    fill_pattern<<<1024, 256, 0, stream>>>((uint32_t*)d_out, (size_t)out_size / 2);
    return;
  }

  detect_kernel<<<1, 256, 0, stream>>>(d_in[3], d_in[2], d_in[4], d_in[6], d_in[8], d_in[10], hdr, bias);

  convert_kernel<<<4096, 256, 0, stream>>>(d_in[0], d_in[1], d_in[3], d_in[5], d_in[7], d_in[9],
                                           dec_b, src_b, Wb, hdr, useConvW);

  const void* Wq = useConvW ? (const void*)(Wb + 0 * 1048576) : (const void*)d_in[3];
  const void* Wk = useConvW ? (const void*)(Wb + 1 * 1048576) : (const void*)d_in[5];
  const void* Wv = useConvW ? (const void*)(Wb + 2 * 1048576) : (const void*)d_in[7];
  const void* Wo = useConvW ? (const void*)(Wb + 3 * 1048576) : (const void*)d_in[9];

  gemm_qkv<<<1536, 256, 0, stream>>>(dec_b, src_b, Wq, Wk, Wv, bias, hdr, Q, K, V, useConvW);

  attn_kernel<<<256, 1024, 0, stream>>>(Q, K, V, hdr, AP, Wm);

  wtrans_kernel<<<dim3(16, 32), 256, 0, stream>>>(Wm, hdr, d_out);

  gemm_bt<MO><<<512, 256, 0, stream>>>(AP, Wo, bias + 3072, hdr, d_out, 1.f, useConvW);
}